// Round 10
// baseline (36997.498 us; speedup 1.0000x reference)
//
#include <hip/hip_runtime.h>
#include <math.h>

typedef short  s16x8 __attribute__((ext_vector_type(8)));
typedef float  f32x4 __attribute__((ext_vector_type(4)));
typedef unsigned short u16;
typedef unsigned long long u64;

#define MFMA16(a, b, c) __builtin_amdgcn_mfma_f32_16x16x32_bf16((a), (b), (c), 0, 0, 0)

#define BB 128
#define SS 512
#define HH 512
#define VV 30
#define TT 64

#define SC_SYS  __HIP_MEMORY_SCOPE_SYSTEM

__device__ __forceinline__ float b2f(u16 v) {
  union { unsigned int u; float f; } c; c.u = ((unsigned int)v) << 16; return c.f;
}
__device__ __forceinline__ u16 f2b(float f) {
  union { float f; unsigned int u; } c; c.f = f;
  unsigned int r = (c.u + 0x7FFFu + ((c.u >> 16) & 1u)) >> 16;
  return (u16)r;
}
__device__ __forceinline__ float sigm(float x) { return 1.f / (1.f + expf(-x)); }
__device__ __forceinline__ s16x8 ldf(const u16* p) { return *(const s16x8*)p; }

// ---- coherent (MALL-level) helpers for cross-block data ----
__device__ __forceinline__ u64  ld64c(const u64* p)      { return __hip_atomic_load(p, __ATOMIC_RELAXED, SC_SYS); }
__device__ __forceinline__ void st64c(u64* p, u64 v)     { __hip_atomic_store(p, v, __ATOMIC_RELAXED, SC_SYS); }
__device__ __forceinline__ void stf32c(float* p, float v){ __hip_atomic_store(p, v, __ATOMIC_RELAXED, SC_SYS); }
__device__ __forceinline__ float ldf32c(const float* p)  { return __hip_atomic_load(p, __ATOMIC_RELAXED, SC_SYS); }
__device__ __forceinline__ void sti32c(int* p, int v)    { __hip_atomic_store(p, v, __ATOMIC_RELAXED, SC_SYS); }
__device__ __forceinline__ int  ldi32c(const int* p)     { return __hip_atomic_load(p, __ATOMIC_RELAXED, SC_SYS); }
__device__ __forceinline__ void stf32(float* p, float v) { *p = v; }

// ---------------------------------------------------------------------
// Dataflow synchronization (verified R6-R8): per-producer-group monotone
// system-scope counters. waitp(): relaxed poll + timeout.
// ---------------------------------------------------------------------
__device__ unsigned int g_cnt[8];
__device__ float g_smx[SS], g_ssum[SS];

#define C_L0 0
#define C_L1 1
#define C_G0 2
#define C_G1 3
#define C_SIM 4
#define C_SMX 5
#define C_ATT 6

__device__ __forceinline__ void waitp(int idx, int target) {
  if (target <= 0) return;
  unsigned long long t0 = __builtin_amdgcn_s_memrealtime();
  while ((int)__hip_atomic_load(&g_cnt[idx], __ATOMIC_RELAXED, SC_SYS) < target) {
    __builtin_amdgcn_s_sleep(1);
    if (__builtin_amdgcn_s_memrealtime() - t0 > (1ull << 21)) break;
  }
}
__device__ __forceinline__ void waitc2(int i1, int t1, int i2, int t2) {
  if (threadIdx.x == 0) { waitp(i1, t1); waitp(i2, t2); }
  __syncthreads();
}
__device__ __forceinline__ void waitc3(int i1, int t1, int i2, int t2, int i3, int t3) {
  if (threadIdx.x == 0) { waitp(i1, t1); waitp(i2, t2); waitp(i3, t3); }
  __syncthreads();
}
__device__ __forceinline__ void waitc4(int i1, int t1, int i2, int t2, int i3, int t3, int i4, int t4) {
  if (threadIdx.x == 0) { waitp(i1, t1); waitp(i2, t2); waitp(i3, t3); waitp(i4, t4); }
  __syncthreads();
}
__device__ __forceinline__ void arrive(int idx) {
  __syncthreads();
  if (threadIdx.x == 0) {
    asm volatile("s_waitcnt vmcnt(0) lgkmcnt(0)" ::: "memory");
    __hip_atomic_fetch_add(&g_cnt[idx], 1u, __ATOMIC_RELAXED, SC_SYS);
  }
}

// ---------------------------------------------------------------------
// State buffers: chunked SBUF layout u16 SBUF[32][128][32] (verified R8).
// Chunk (g,m) = one 64B line: u16 0..15 = hi of cols [16g,16g+16),
// 16..31 = lo. Producers write FULL LINES via LDS-transpose + u64
// stores. Consumers stage linearly (R8, verified).
//
// LDS per buffer: 128 rows x 512B; slot s of row at (s ^ (row&15)).
// Double-buffered (2 x 32768 u16 = 128KB) so kc+1 global loads issue
// before kc's MFMA (T14 latency hiding).
// ---------------------------------------------------------------------
__device__ __forceinline__ s16x8 ldl(const u16* buf, int row, int slot) {
  return *(const s16x8*)&buf[(row << 8) + ((slot ^ (row & 15)) << 3)];
}

// coalesced global->reg loads of 64 SBUF rows (one source) for K-chunk kc
__device__ __forceinline__ void ldchunk64(u64* v, const u16* SRC, int mbase, int kc) {
  const int t = threadIdx.x;
  const u64* base = (const u64*)SRC;
#pragma unroll
  for (int j = 0; j < 16; ++j)
    v[j] = ld64c(base + (size_t)((kc * 8 + (j >> 1)) * 128 + mbase + (j & 1) * 32) * 8 + t);
}
// reg->LDS for those 64 rows at row offset rowoff (R8-verified mapping)
__device__ __forceinline__ void stchunk64(u16* buf, int rowoff, const u64* v) {
  const int t = threadIdx.x;
#pragma unroll
  for (int j = 0; j < 16; ++j) {
    const int gl = j >> 1;
    const int row = rowoff + (j & 1) * 32 + (t >> 3);
    const int w = t & 7;
    const int s = ((w & 4) << 2) + 2 * gl + ((w >> 1) & 1);
    *(u64*)&buf[(row << 8) + ((s ^ (row & 15)) << 3) + ((w & 1) << 2)] = v[j];
  }
}
// all 128 rows (enc-l0)
__device__ __forceinline__ void ldchunk128(u64* v, const u16* SRC, int kc) {
  const int t = threadIdx.x;
  const u64* base = (const u64*)SRC;
#pragma unroll
  for (int j = 0; j < 32; ++j)
    v[j] = ld64c(base + (size_t)((kc * 8 + (j >> 2)) * 128 + (j & 3) * 32) * 8 + t);
}
__device__ __forceinline__ void stchunk128(u16* buf, const u64* v) {
  const int t = threadIdx.x;
#pragma unroll
  for (int j = 0; j < 32; ++j) {
    const int gl = j >> 2;
    const int row = (j & 3) * 32 + (t >> 3);
    const int w = t & 7;
    const int s = ((w & 4) << 2) + 2 * gl + ((w >> 1) & 1);
    *(u64*)&buf[(row << 8) + ((s ^ (row & 15)) << 3) + ((w & 1) << 2)] = v[j];
  }
}

// Split-f32 format per logical row of K=512: hi = bf16(v), lo = bf16(v-hi).
// GEMM does hi*hi + hi*lo + lo*hi (Markidis).

// =====================================================================
// Dual-input GRU cell (enc-l1 / decoder): 64 block-roles x 256 thr.
// Double-buffered staging; coalesced SBUF publish via LDS transpose.
// =====================================================================
template <bool GATHER, bool COH_H>
__device__ __forceinline__ void gru_dual_staged(
    int bx, u16* SM,
    const u16* __restrict__ A1s, const int* __restrict__ gather,
    const u16* __restrict__ A2s,
    const u16* __restrict__ Wihs, const u16* __restrict__ Whhs,
    const float* __restrict__ bih, const float* __restrict__ bhh,
    float* __restrict__ hf, u16* __restrict__ hs_new,
    u16* __restrict__ oe, size_t oe_mstride)
{
  const int tid  = threadIdx.x;
  const int wave = tid >> 6, lane = tid & 63;
  const int lrow = lane & 15, lq = lane >> 4;
  const int gidx = bx >> 1;             // 16-col group
  const int j0 = gidx * 16;
  const int mbase = (bx & 1) * 64;
  const int lr = wave * 16 + lrow;      // local row 0..63
  const int m0 = mbase + wave * 16;

  const u16* a1p = nullptr;
  if (GATHER)
    a1p = A1s + (size_t)ldi32c(&gather[m0 + lrow]) * 1024 + lq * 8;

  const u16* bp[6];
#pragma unroll
  for (int t = 0; t < 6; ++t) {
    int g = (t < 3) ? t : t - 3;
    const u16* W = (t < 3) ? Wihs : Whhs;
    bp[t] = W + (size_t)(g * HH + j0 + lrow) * 1024 + lq * 8;
  }

  f32x4 acc[6];
#pragma unroll
  for (int t = 0; t < 6; ++t) acc[t] = (f32x4){0.f, 0.f, 0.f, 0.f};

  u64 v1[16], v2[16];
  if (!GATHER) ldchunk64(v1, A1s, mbase, 0);
  ldchunk64(v2, A2s, mbase, 0);
  if (!GATHER) stchunk64(SM, 0, v1);
  stchunk64(SM, 64, v2);
  __syncthreads();

  for (int kc = 0; kc < 4; ++kc) {
    u16* buf = SM + ((kc & 1) << 15);
    if (kc < 3) {                      // issue next-chunk loads EARLY
      if (!GATHER) ldchunk64(v1, A1s, mbase, kc + 1);
      ldchunk64(v2, A2s, mbase, kc + 1);
    }
#pragma unroll
    for (int ki = 0; ki < 4; ++ki) {
      const int sl = ki * 4 + lq;
      s16x8 a1h, a1l;
      if (GATHER) { a1h = ldf(a1p); a1l = ldf(a1p + 512); a1p += 32; }
      else        { a1h = ldl(buf, lr, sl); a1l = ldl(buf, lr, 16 + sl); }
      s16x8 a2h = ldl(buf, 64 + lr, sl), a2l = ldl(buf, 64 + lr, 16 + sl);
#pragma unroll
      for (int t = 0; t < 6; ++t) {
        s16x8 bh = ldf(bp[t]), bl = ldf(bp[t] + 512); bp[t] += 32;
        s16x8 ah = (t < 3) ? a1h : a2h;
        s16x8 al = (t < 3) ? a1l : a2l;
        acc[t] = MFMA16(ah, bh, acc[t]);
        acc[t] = MFMA16(ah, bl, acc[t]);
        acc[t] = MFMA16(al, bh, acc[t]);
      }
    }
    if (kc < 3) {
      __syncthreads();
      u16* nb = SM + (((kc + 1) & 1) << 15);
      if (!GATHER) stchunk64(nb, 0, v1);
      stchunk64(nb, 64, v2);
      __syncthreads();
    }
  }

  const int c = j0 + lrow;
  const float bir = bih[c], biz = bih[HH + c], bin = bih[2 * HH + c];
  const float bhr = bhh[c], bhz = bhh[HH + c], bhn = bhh[2 * HH + c];
#pragma unroll
  for (int r = 0; r < 4; ++r) {
    int m = mbase + wave * 16 + lq * 4 + r;
    float ir = acc[0][r] + bir, iz = acc[1][r] + biz, inn = acc[2][r] + bin;
    float hr = acc[3][r] + bhr, hz = acc[4][r] + bhz, hn = acc[5][r] + bhn;
    float rr = sigm(ir + hr);
    float zz = sigm(iz + hz);
    float nn = tanhf(inn + rr * hn);
    float hp = COH_H ? ldf32c(&hf[(size_t)m * HH + c]) : hf[(size_t)m * HH + c];
    float hv = (1.f - zz) * nn + zz * hp;
    if (COH_H) stf32c(&hf[(size_t)m * HH + c], hv);
    else       stf32(&hf[(size_t)m * HH + c], hv);
    u16 hi = f2b(hv);
    int ml = m - mbase;                 // TB overlay on buf0 (dead region)
    SM[ml * 32 + lrow]      = hi;
    SM[ml * 32 + 16 + lrow] = f2b(hv - b2f(hi));
    if (oe) oe[(size_t)m * oe_mstride + c] = hi;   // read only by next kernel
  }
  __syncthreads();
  {
    u64* dst = (u64*)hs_new + (size_t)(gidx * 128 + mbase) * 8;
    const u64* src = (const u64*)SM;
    st64c(dst + tid,       src[tid]);
    st64c(dst + 256 + tid, src[256 + tid]);
  }
}

// =====================================================================
// Encoder layer-0: 16 block-roles x 32 cols. gh via MFMA (staged split
// A, cached split Whh0); gi inline f32 (K=2, exact).
// =====================================================================
__device__ __forceinline__ void gru_l0_staged(
    int bx, int p, u16* SM,
    const float* __restrict__ x, const float* __restrict__ Wih0,
    const u16* __restrict__ Whh0s,
    const float* __restrict__ bih0, const float* __restrict__ bhh0,
    const u16* __restrict__ As,
    float* __restrict__ af, u16* __restrict__ as_new)
{
  const int tid  = threadIdx.x;
  const int wave = tid >> 6, lane = tid & 63;
  const int lrow = lane & 15, lq = lane >> 4;
  const int j0 = bx * 32;
  const int mw = wave * 32;
  const int r0 = mw + lrow, r1 = mw + 16 + lrow;

  const u16* bp[6];   // [jg*3+g]
#pragma unroll
  for (int u = 0; u < 6; ++u) {
    int jg = u / 3, g = u % 3;
    bp[u] = Whh0s + (size_t)(g * HH + j0 + jg * 16 + lrow) * 1024 + lq * 8;
  }

  f32x4 acc[2][2][3];   // [tm][jg][gate]
#pragma unroll
  for (int i = 0; i < 2; ++i)
#pragma unroll
    for (int jg = 0; jg < 2; ++jg)
#pragma unroll
      for (int g = 0; g < 3; ++g) acc[i][jg][g] = (f32x4){0.f, 0.f, 0.f, 0.f};

  u64 v[32];
  ldchunk128(v, As, 0);
  stchunk128(SM, v);
  __syncthreads();

  for (int kc = 0; kc < 4; ++kc) {
    u16* buf = SM + ((kc & 1) << 15);
    if (kc < 3) ldchunk128(v, As, kc + 1);
#pragma unroll
    for (int ki = 0; ki < 4; ++ki) {
      const int sl = ki * 4 + lq;
      s16x8 a0h = ldl(buf, r0, sl), a0l = ldl(buf, r0, 16 + sl);
      s16x8 a1h = ldl(buf, r1, sl), a1l = ldl(buf, r1, 16 + sl);
#pragma unroll
      for (int jg = 0; jg < 2; ++jg)
#pragma unroll
        for (int g = 0; g < 3; ++g) {
          const u16* w = bp[jg * 3 + g];
          s16x8 bh = ldf(w), bl = ldf(w + 512); bp[jg * 3 + g] = w + 32;
          acc[0][jg][g] = MFMA16(a0h, bh, acc[0][jg][g]);
          acc[0][jg][g] = MFMA16(a0h, bl, acc[0][jg][g]);
          acc[0][jg][g] = MFMA16(a0l, bh, acc[0][jg][g]);
          acc[1][jg][g] = MFMA16(a1h, bh, acc[1][jg][g]);
          acc[1][jg][g] = MFMA16(a1h, bl, acc[1][jg][g]);
          acc[1][jg][g] = MFMA16(a1l, bh, acc[1][jg][g]);
        }
    }
    if (kc < 3) {
      __syncthreads();
      stchunk128(SM + (((kc + 1) & 1) << 15), v);
      __syncthreads();
    }
  }

#pragma unroll
  for (int tm = 0; tm < 2; ++tm) {
#pragma unroll
    for (int r = 0; r < 4; ++r) {
      int m = mw + tm * 16 + lq * 4 + r;
      float x0 = x[((size_t)m * SS + p) * 2];
      float x1 = x[((size_t)m * SS + p) * 2 + 1];
#pragma unroll
      for (int jg = 0; jg < 2; ++jg) {
        const int c = j0 + jg * 16 + lrow;
        const float bir = bih0[c], biz = bih0[HH + c], bin = bih0[2 * HH + c];
        const float bhr = bhh0[c], bhz = bhh0[HH + c], bhn = bhh0[2 * HH + c];
        float ir  = bir + x0 * Wih0[(size_t)c * 2]            + x1 * Wih0[(size_t)c * 2 + 1];
        float iz  = biz + x0 * Wih0[(size_t)(HH + c) * 2]     + x1 * Wih0[(size_t)(HH + c) * 2 + 1];
        float inn = bin + x0 * Wih0[(size_t)(2 * HH + c) * 2] + x1 * Wih0[(size_t)(2 * HH + c) * 2 + 1];
        float hr = acc[tm][jg][0][r] + bhr;
        float hz = acc[tm][jg][1][r] + bhz;
        float hn = acc[tm][jg][2][r] + bhn;
        float rr = sigm(ir + hr);
        float zz = sigm(iz + hz);
        float nn = tanhf(inn + rr * hn);
        float hp = af[(size_t)m * HH + c];      // same-thread RMW
        float hv = (1.f - zz) * nn + zz * hp;
        af[(size_t)m * HH + c] = hv;
        u16 hi = f2b(hv);
        SM[jg * 4096 + m * 32 + lrow]      = hi;     // TB overlay on buf0
        SM[jg * 4096 + m * 32 + 16 + lrow] = f2b(hv - b2f(hi));
      }
    }
  }
  __syncthreads();
  {
    const u64* src = (const u64*)SM;
#pragma unroll
    for (int jg = 0; jg < 2; ++jg) {
      u64* dst = (u64*)as_new + (size_t)((2 * bx + jg) * 128) * 8;
      // R9 BUG FIX: each jg group = 128 chunks x 8 u64 = 1024 u64 in the
      // overlay, so the source offset is jg*1024 (was jg*512 -> corrupted
      // the odd 16-col group of every published a-state).
#pragma unroll
      for (int k = 0; k < 4; ++k)
        st64c(dst + k * 256 + tid, src[jg * 1024 + k * 256 + tid]);
    }
  }
}

// sim[s][b] = dot(out_enc[b,s,:], n1[b,:]). b = bx>>1, s-half = bx&1.
__device__ __forceinline__ void sim_block(
    int bx, const float* __restrict__ n1f, const u16* __restrict__ oe,
    float* __restrict__ simt)
{
  const int b = bx >> 1, sc = bx & 1;
  const int wave = threadIdx.x >> 6, lane = threadIdx.x & 63;
  float xr[8];
  const u64* xp = (const u64*)(n1f + (size_t)b * HH + lane * 8);
#pragma unroll
  for (int j = 0; j < 4; ++j) {
    union { u64 q; float f[2]; } u; u.q = ld64c(xp + j);
    xr[2 * j] = u.f[0]; xr[2 * j + 1] = u.f[1];
  }
  int s0 = sc * 256 + wave * 64;
  for (int i = 0; i < 64; ++i) {
    int s = s0 + i;
    s16x8 ov = *(const s16x8*)(oe + ((size_t)b * SS + s) * HH + lane * 8);
    float acc = 0.f;
#pragma unroll
    for (int j = 0; j < 8; ++j) acc += xr[j] * b2f((u16)ov[j]);
    for (int off = 32; off; off >>= 1) acc += __shfl_down(acc, off);
    if (lane == 0) stf32c(&simt[(size_t)s * BB + b], acc);
  }
}

// Per-s softmax stats over batch dim (reference dim=0 quirk), computed ONCE.
__device__ __forceinline__ void smax_block(int bx, const float* __restrict__ simt)
{
  const int wave = threadIdx.x >> 6, lane = threadIdx.x & 63;
  const int s = bx * 4 + wave;
  union { u64 q; float f[2]; } u;
  u.q = ld64c((const u64*)&simt[(size_t)s * BB + lane * 2]);
  float mx = fmaxf(u.f[0], u.f[1]);
  for (int off = 32; off; off >>= 1) mx = fmaxf(mx, __shfl_xor(mx, off));
  float e = expf(u.f[0] - mx) + expf(u.f[1] - mx);
  for (int off = 32; off; off >>= 1) e += __shfl_xor(e, off);
  if (lane == 0) { stf32c(&g_smx[s], mx); stf32c(&g_ssum[s], e); }
}

// attention -> logits -> argmax feedback. One block per batch element.
__device__ __forceinline__ void attn_block(
    int b, int tstep, const float* __restrict__ simt, const float* __restrict__ n1f,
    const u16* __restrict__ oe, const float* __restrict__ fcW,
    const float* __restrict__ fcb, float* __restrict__ dout,
    int* __restrict__ tok)
{
  __shared__ float wsm[SS];
  __shared__ float xv[2 * HH];
  __shared__ float lg[32];
  const int t = threadIdx.x;

  for (int s = t; s < SS; s += 256) {
    float sv = ldf32c(&simt[(size_t)s * BB + b]);
    float mx = ldf32c(&g_smx[s]);
    float sm = ldf32c(&g_ssum[s]);
    wsm[s] = expf(sv - mx) / sm;
  }
  xv[t]       = ldf32c(&n1f[(size_t)b * HH + t]);
  xv[t + 256] = ldf32c(&n1f[(size_t)b * HH + t + 256]);
  __syncthreads();

  {
    float a0 = 0.f, a1 = 0.f;
    const u16* base = oe + (size_t)b * SS * HH;   // read-only: cached
    for (int s = 0; s < SS; ++s) {
      float w = wsm[s];
      a0 += w * b2f(base[(size_t)s * HH + t]);
      a1 += w * b2f(base[(size_t)s * HH + t + 256]);
    }
    xv[HH + t]       = a0;
    xv[HH + t + 256] = a1;
  }
  __syncthreads();

  int wave = t >> 6, lane = t & 63;
  for (int v = wave; v < VV; v += 4) {
    const float* wr = fcW + (size_t)v * (2 * HH);
    float acc = 0.f;
#pragma unroll
    for (int i = 0; i < 16; ++i) acc += xv[i * 64 + lane] * wr[i * 64 + lane];
    for (int off = 32; off; off >>= 1) acc += __shfl_down(acc, off);
    if (lane == 0) {
      float lv = acc + fcb[v];
      lg[v] = lv;
      dout[(size_t)b * (TT * VV) + (size_t)tstep * VV + v] = lv;  // host-read
    }
  }
  __syncthreads();

  if (t == 0) {
    float best = lg[0]; int bi = 0;
    for (int v = 1; v < VV; ++v) if (lg[v] > best) { best = lg[v]; bi = v; }
    sti32c(&tok[b], bi);
  }
}

// =====================================================================
// Persistent encoder: 80 blocks (16 l0 + 64 l1), 513 phases.
// l0@p needs C_L0>=16p (a_{p-1} complete) + C_L1>=64(p-1) (buffer free).
// l1@p needs the same union. They overlap across a phase.
// =====================================================================
__global__ __launch_bounds__(256) void enc_persist(
    const float* __restrict__ x, const float* __restrict__ Wih0,
    const u16* __restrict__ Whh0s,
    const float* __restrict__ bih0, const float* __restrict__ bhh0,
    const u16* __restrict__ Wih1s, const u16* __restrict__ Whh1s,
    const float* __restrict__ bih1, const float* __restrict__ bhh1,
    u16* ABF0, u16* ABF1, float* af,
    u16* CBF0, u16* CBF1, float* cf,
    u16* out_enc)
{
  __shared__ u16 SM[65536];
  const int bx = blockIdx.x;
  const u16* pa = ABF0; u16* pa_n = ABF1;
  const u16* pc = CBF0; u16* pc_n = CBF1;
  for (int p = 0; p <= SS; ++p) {
    waitc2(C_L0, 16 * p, C_L1, 64 * (p - 1));
    if (bx < 16) {
      if (p < SS) {
        gru_l0_staged(bx, p, SM, x, Wih0, Whh0s, bih0, bhh0, pa, af, pa_n);
        arrive(C_L0);
      }
    } else {
      if (p > 0) {
        u16* oe = out_enc + (size_t)(p - 1) * HH;
        gru_dual_staged<false, false>(bx - 16, SM, pa, nullptr, pc,
                                      Wih1s, Whh1s, bih1, bhh1,
                                      cf, pc_n, oe, (size_t)SS * HH);
        arrive(C_L1);
      }
    }
    const u16* tp;
    tp = pa; pa = pa_n; pa_n = (u16*)tp;
    tp = pc; pc = pc_n; pc_n = (u16*)tp;
  }
}

// =====================================================================
// Persistent decoder: 256 blocks, 64 steps x 5 dataflow phases (R7/R8).
// =====================================================================
__global__ __launch_bounds__(256) void dec_persist(
    const u16* __restrict__ EMBs, int* tok,
    const u16* __restrict__ WdIH0, const u16* __restrict__ WdHH0,
    const float* __restrict__ dbih0, const float* __restrict__ dbhh0,
    const u16* __restrict__ WdIH1, const u16* __restrict__ WdHH1,
    const float* __restrict__ dbih1, const float* __restrict__ dbhh1,
    float* af, float* cf,
    u16* D0A, u16* D0B, u16* D1A, u16* D1B,
    const u16* __restrict__ oe, float* simt,
    const float* __restrict__ fcW, const float* __restrict__ fcb,
    float* dout)
{
  __shared__ u16 SM[65536];
  const int bx = blockIdx.x;
  const u16* d0c = D0A; u16* d0n = D0B;
  const u16* d1c = D1A; u16* d1n = D1B;
  for (int t = 0; t < TT; ++t) {
    if (bx < 64) {
      waitc3(C_G0, 64 * t, C_ATT, 128 * t, C_G1, 64 * (t - 1));
      gru_dual_staged<true, false>(bx, SM, EMBs, tok, d0c,
                                   WdIH0, WdHH0, dbih0, dbhh0, af, d0n,
                                   nullptr, 0);
      arrive(C_G0);
    }
    { const u16* tp = d0c; d0c = d0n; d0n = (u16*)tp; }

    if (bx < 64) {
      waitc4(C_G0, 64 * (t + 1), C_G1, 64 * t, C_SIM, 256 * t, C_ATT, 128 * t);
      gru_dual_staged<false, true>(bx, SM, d0c, nullptr, d1c,
                                   WdIH1, WdHH1, dbih1, dbhh1, cf, d1n,
                                   nullptr, 0);
      arrive(C_G1);
    }
    { const u16* tp = d1c; d1c = d1n; d1n = (u16*)tp; }

    waitc3(C_G1, 64 * (t + 1), C_SMX, 128 * t, C_ATT, 128 * t);
    sim_block(bx, cf, oe, simt);
    arrive(C_SIM);

    if (bx < 128) {
      waitc2(C_SIM, 256 * (t + 1), C_ATT, 128 * t);
      smax_block(bx, simt);
      arrive(C_SMX);
    }

    if (bx < BB) {
      waitc4(C_SMX, 128 * (t + 1), C_SIM, 256 * (t + 1),
             C_G1, 64 * (t + 1), C_G0, 64 * (t + 1));
      attn_block(bx, t, simt, cf, oe, fcW, fcb, dout, tok);
      arrive(C_ATT);
    }
  }
}

// Split weights (row-major layout: row r -> [hi x512 | lo x512]).
__global__ __launch_bounds__(256) void splitall(
    const float* __restrict__ s0, u16* d0, const float* __restrict__ s1, u16* d1,
    const float* __restrict__ s2, u16* d2, const float* __restrict__ s3, u16* d3,
    const float* __restrict__ s4, u16* d4, const float* __restrict__ s5, u16* d5,
    const float* __restrict__ s6, u16* d6, const float* __restrict__ s7, u16* d7)
{
  const int WN = 3 * HH * HH;  // 786432
  int i = blockIdx.x * 256 + threadIdx.x;
  const float* s; u16* d; int j;
  if      (i < 1 * WN) { s = s0; d = d0; j = i; }
  else if (i < 2 * WN) { s = s1; d = d1; j = i - 1 * WN; }
  else if (i < 3 * WN) { s = s2; d = d2; j = i - 2 * WN; }
  else if (i < 4 * WN) { s = s3; d = d3; j = i - 3 * WN; }
  else if (i < 5 * WN) { s = s4; d = d4; j = i - 4 * WN; }
  else if (i < 6 * WN) { s = s5; d = d5; j = i - 5 * WN; }
  else if (i < 7 * WN) { s = s6; d = d6; j = i - 6 * WN; }
  else { j = i - 7 * WN; if (j >= VV * HH) return; s = s7; d = d7; }
  int r = j >> 9, k = j & 511;
  float v = s[j];
  u16 hi = f2b(v);
  d[(size_t)r * 1024 + k]       = hi;
  d[(size_t)r * 1024 + 512 + k] = f2b(v - b2f(hi));
}

__global__ __launch_bounds__(256) void initk(
    float* af, float* cf, u16* b0, u16* b1, u16* b2, u16* b3, int* tok)
{
  int i = blockIdx.x * 256 + threadIdx.x;   // 131072 threads
  b0[i] = 0; b1[i] = 0; b2[i] = 0; b3[i] = 0;
  if (i < BB * HH) { af[i] = 0.f; cf[i] = 0.f; }
  if (i < BB) tok[i] = 0;
  if (i < 8) g_cnt[i] = 0;
}

__global__ __launch_bounds__(256) void finalize(
    const float* __restrict__ d0, const float* __restrict__ d1,
    float* __restrict__ oh)
{
  int i = blockIdx.x * 256 + threadIdx.x;
  oh[i]           = d0[i];
  oh[BB * HH + i] = d1[i];
}

extern "C" void kernel_launch(void* const* d_in, const int* in_sizes, int n_in,
                              void* d_out, int out_size, void* d_ws, size_t ws_size,
                              hipStream_t stream) {
  const float* x     = (const float*)d_in[0];
  const float* emb   = (const float*)d_in[1];
  const float* eWih0 = (const float*)d_in[2];
  const float* eWhh0 = (const float*)d_in[3];
  const float* ebih0 = (const float*)d_in[4];
  const float* ebhh0 = (const float*)d_in[5];
  const float* eWih1 = (const float*)d_in[6];
  const float* eWhh1 = (const float*)d_in[7];
  const float* ebih1 = (const float*)d_in[8];
  const float* ebhh1 = (const float*)d_in[9];
  const float* dWih0 = (const float*)d_in[10];
  const float* dWhh0 = (const float*)d_in[11];
  const float* dbih0 = (const float*)d_in[12];
  const float* dbhh0 = (const float*)d_in[13];
  const float* dWih1 = (const float*)d_in[14];
  const float* dWhh1 = (const float*)d_in[15];
  const float* dbih1 = (const float*)d_in[16];
  const float* dbhh1 = (const float*)d_in[17];
  const float* fcW   = (const float*)d_in[18];
  const float* fcb   = (const float*)d_in[19];
  float* dout = (float*)d_out;

  char* wsb = (char*)d_ws;
  float* af   = (float*)(wsb + 0);          // 128x512 f32 (a / d0 state, RMW)
  float* cf   = (float*)(wsb + 262144);     // 128x512 f32 (c / d1 state, RMW)
  u16* ABF0   = (u16*)(wsb + 524288);       // SBUF-layout states, 256KB each
  u16* ABF1   = (u16*)(wsb + 786432);
  u16* CBF0   = (u16*)(wsb + 1048576);
  u16* CBF1   = (u16*)(wsb + 1310720);
  int* tok    = (int*)(wsb + 1572864);
  float* simt = (float*)(wsb + 1573376);    // [S][B] f32, 256 KB
  u16* WeHH0  = (u16*)(wsb + 1835520);      // split weights, 3 MB each
  u16* WeIH1  = (u16*)(wsb + 4981248);
  u16* WeHH1  = (u16*)(wsb + 8126976);
  u16* WdIH0  = (u16*)(wsb + 11272704);
  u16* WdHH0  = (u16*)(wsb + 14418432);
  u16* WdIH1  = (u16*)(wsb + 17564160);
  u16* WdHH1  = (u16*)(wsb + 20709888);
  u16* EMBs   = (u16*)(wsb + 23855616);     // 30x1024 u16, row-major layout
  u16* oe     = (u16*)(wsb + 23917056);     // out_enc bf16 [B][S][H], 64 MiB

  initk<<<512, 256, 0, stream>>>(af, cf, ABF0, ABF1, CBF0, CBF1, tok);

  splitall<<<21564, 256, 0, stream>>>(eWhh0, WeHH0, eWih1, WeIH1, eWhh1, WeHH1,
                                      dWih0, WdIH0, dWhh0, WdHH0, dWih1, WdIH1,
                                      dWhh1, WdHH1, emb, EMBs);

  enc_persist<<<80, 256, 0, stream>>>(x, eWih0, WeHH0, ebih0, ebhh0,
                                      WeIH1, WeHH1, ebih1, ebhh1,
                                      ABF0, ABF1, af, CBF0, CBF1, cf, oe);

  // a_511 SBUF in ABF0 (written p=511); c_511 SBUF in CBF1 (written p=512)
  dec_persist<<<256, 256, 0, stream>>>(EMBs, tok, WdIH0, WdHH0, dbih0, dbhh0,
                                       WdIH1, WdHH1, dbih1, dbhh1,
                                       af, cf, ABF0, ABF1, CBF1, CBF0,
                                       oe, simt, fcW, fcb, dout);

  finalize<<<256, 256, 0, stream>>>(af, cf, dout + (size_t)BB * TT * VV);
}

// Round 11
// 25538.503 us; speedup vs baseline: 1.4487x; 1.4487x over previous
//
#include <hip/hip_runtime.h>
#include <math.h>

typedef short  s16x8 __attribute__((ext_vector_type(8)));
typedef float  f32x4 __attribute__((ext_vector_type(4)));
typedef unsigned short u16;
typedef unsigned long long u64;

#define MFMA16(a, b, c) __builtin_amdgcn_mfma_f32_16x16x32_bf16((a), (b), (c), 0, 0, 0)

#define BB 128
#define SS 512
#define HH 512
#define VV 30
#define TT 64

#define SC_SYS  __HIP_MEMORY_SCOPE_SYSTEM

__device__ __forceinline__ float b2f(u16 v) {
  union { unsigned int u; float f; } c; c.u = ((unsigned int)v) << 16; return c.f;
}
__device__ __forceinline__ u16 f2b(float f) {
  union { float f; unsigned int u; } c; c.f = f;
  unsigned int r = (c.u + 0x7FFFu + ((c.u >> 16) & 1u)) >> 16;
  return (u16)r;
}
__device__ __forceinline__ float sigm(float x) { return 1.f / (1.f + expf(-x)); }
__device__ __forceinline__ s16x8 ldf(const u16* p) { return *(const s16x8*)p; }

// ---- coherent (MALL-level) helpers for cross-block data ----
__device__ __forceinline__ u64  ld64c(const u64* p)      { return __hip_atomic_load(p, __ATOMIC_RELAXED, SC_SYS); }
__device__ __forceinline__ void st64c(u64* p, u64 v)     { __hip_atomic_store(p, v, __ATOMIC_RELAXED, SC_SYS); }
__device__ __forceinline__ void stf32c(float* p, float v){ __hip_atomic_store(p, v, __ATOMIC_RELAXED, SC_SYS); }
__device__ __forceinline__ float ldf32c(const float* p)  { return __hip_atomic_load(p, __ATOMIC_RELAXED, SC_SYS); }
__device__ __forceinline__ void sti32c(int* p, int v)    { __hip_atomic_store(p, v, __ATOMIC_RELAXED, SC_SYS); }
__device__ __forceinline__ int  ldi32c(const int* p)     { return __hip_atomic_load(p, __ATOMIC_RELAXED, SC_SYS); }
__device__ __forceinline__ void stf32(float* p, float v) { *p = v; }

// ---------------------------------------------------------------------
// Dataflow synchronization (verified R6-R8): per-producer-group monotone
// system-scope counters, now PADDED to one 64B line each (R8 had all 8
// counters on one line -> every arrive RMW + every poll contended on a
// single MALL slice). waitp(): relaxed poll + timeout.
// ---------------------------------------------------------------------
__device__ unsigned int g_cnt[128];   // counter idx -> g_cnt[idx*16]
__device__ float g_smx[SS], g_ssum[SS];

#define C_L0 0
#define C_L1 1
#define C_G0 2
#define C_G1 3
#define C_SIM 4
#define C_SMX 5
#define C_ATT 6

__device__ __forceinline__ void waitp(int idx, int target) {
  if (target <= 0) return;
  unsigned long long t0 = __builtin_amdgcn_s_memrealtime();
  while ((int)__hip_atomic_load(&g_cnt[idx * 16], __ATOMIC_RELAXED, SC_SYS) < target) {
    __builtin_amdgcn_s_sleep(1);
    if (__builtin_amdgcn_s_memrealtime() - t0 > (1ull << 21)) break;
  }
}
__device__ __forceinline__ void waitc2(int i1, int t1, int i2, int t2) {
  if (threadIdx.x == 0) { waitp(i1, t1); waitp(i2, t2); }
  __syncthreads();
}
__device__ __forceinline__ void waitc3(int i1, int t1, int i2, int t2, int i3, int t3) {
  if (threadIdx.x == 0) { waitp(i1, t1); waitp(i2, t2); waitp(i3, t3); }
  __syncthreads();
}
__device__ __forceinline__ void waitc4(int i1, int t1, int i2, int t2, int i3, int t3, int i4, int t4) {
  if (threadIdx.x == 0) { waitp(i1, t1); waitp(i2, t2); waitp(i3, t3); waitp(i4, t4); }
  __syncthreads();
}
__device__ __forceinline__ void arrive(int idx) {
  __syncthreads();
  if (threadIdx.x == 0) {
    asm volatile("s_waitcnt vmcnt(0) lgkmcnt(0)" ::: "memory");
    __hip_atomic_fetch_add(&g_cnt[idx * 16], 1u, __ATOMIC_RELAXED, SC_SYS);
  }
}

// ---------------------------------------------------------------------
// State buffers: chunked SBUF layout u16 SBUF[32][128][32] (verified R8).
// Chunk (g,m) = one 64B line: u16 0..15 = hi of cols [16g,16g+16),
// 16..31 = lo. Consumers stage linearly (R8, verified). Producers (new
// in R11) write FULL LINES: epilogue values -> LDS overlay in the dead
// staging buffer -> contiguous u64 system stores. (R8 issued ~1K
// scattered u16 system stores per wave; the compiler's vmcnt(0) before
// s_barrier serialized their line-RMW drains: ~5-7us of each phase.)
//
// LDS per buffer: 128 rows x 512B; slot s of row at (s ^ (row&15)).
// Single-buffered (R8 — R9's double-buffer cost VGPR/LDS with no gain).
// ---------------------------------------------------------------------
__device__ __forceinline__ s16x8 ldl(const u16* buf, int row, int slot) {
  return *(const s16x8*)&buf[(row << 8) + ((slot ^ (row & 15)) << 3)];
}

// Stage 64 rows (mbase..mbase+63) of one SBUF source for K-chunk kc into
// LDS rows rowoff.. of SM. Coalesced u64 loads + ds_write_b64 (R8).
__device__ __forceinline__ void stage64(u16* SMb, const u16* SRC, int mbase, int kc) {
  const int t = threadIdx.x;
  const u64* base = (const u64*)SRC;
  u64 v[16];
#pragma unroll
  for (int j = 0; j < 16; ++j) {
    const int g = kc * 8 + (j >> 1);
    const int half = j & 1;
    v[j] = ld64c(base + (size_t)(g * 128 + mbase + half * 32) * 8 + t);
  }
#pragma unroll
  for (int j = 0; j < 16; ++j) {
    const int gl = j >> 1, half = j & 1;
    const int row = half * 32 + (t >> 3);
    const int w = t & 7;
    const int s = ((w & 4) << 2) + 2 * gl + ((w >> 1) & 1);
    *(u64*)&SMb[(row << 8) + ((s ^ (row & 15)) << 3) + ((w & 1) << 2)] = v[j];
  }
}

// Stage all 128 rows (enc-l0) for K-chunk kc (R8).
__device__ __forceinline__ void stage128(u16* SM, const u16* SRC, int kc) {
  const int t = threadIdx.x;
  const u64* base = (const u64*)SRC;
  u64 v[32];
#pragma unroll
  for (int j = 0; j < 32; ++j) {
    const int g = kc * 8 + (j >> 2);
    const int q = j & 3;
    v[j] = ld64c(base + (size_t)(g * 128 + q * 32) * 8 + t);
  }
#pragma unroll
  for (int j = 0; j < 32; ++j) {
    const int gl = j >> 2, q = j & 3;
    const int row = q * 32 + (t >> 3);
    const int w = t & 7;
    const int s = ((w & 4) << 2) + 2 * gl + ((w >> 1) & 1);
    *(u64*)&SM[(row << 8) + ((s ^ (row & 15)) << 3) + ((w & 1) << 2)] = v[j];
  }
}

// Split-f32 format per logical row of K=512: hi = bf16(v), lo = bf16(v-hi).
// GEMM does hi*hi + hi*lo + lo*hi (Markidis).

// =====================================================================
// Dual-input GRU cell (enc-l1 / decoder): 64 block-roles x 256 thr.
// R8 staging/MFMA; R11 coalesced publish.
// =====================================================================
template <bool GATHER, bool COH_H>
__device__ __forceinline__ void gru_dual_staged(
    int bx, u16* SM,
    const u16* __restrict__ A1s, const int* __restrict__ gather,
    const u16* __restrict__ A2s,
    const u16* __restrict__ Wihs, const u16* __restrict__ Whhs,
    const float* __restrict__ bih, const float* __restrict__ bhh,
    float* __restrict__ hf, u16* __restrict__ hs_new,
    u16* __restrict__ oe, size_t oe_mstride)
{
  const int tid  = threadIdx.x;
  const int wave = tid >> 6, lane = tid & 63;
  const int lrow = lane & 15, lq = lane >> 4;
  const int gidx = bx >> 1;             // 16-col group
  const int j0 = gidx * 16;
  const int mbase = (bx & 1) * 64;
  const int lr = wave * 16 + lrow;      // local row 0..63
  const int m0 = mbase + wave * 16;

  const u16* a1p = nullptr;
  if (GATHER)
    a1p = A1s + (size_t)ldi32c(&gather[m0 + lrow]) * 1024 + lq * 8;

  const u16* bp[6];
#pragma unroll
  for (int t = 0; t < 6; ++t) {
    int g = (t < 3) ? t : t - 3;
    const u16* W = (t < 3) ? Wihs : Whhs;
    bp[t] = W + (size_t)(g * HH + j0 + lrow) * 1024 + lq * 8;
  }

  f32x4 acc[6];
#pragma unroll
  for (int t = 0; t < 6; ++t) acc[t] = (f32x4){0.f, 0.f, 0.f, 0.f};

  for (int kc = 0; kc < 4; ++kc) {
    if (!GATHER) stage64(SM, A1s, mbase, kc);
    stage64(SM + 64 * 256, A2s, mbase, kc);
    __syncthreads();
#pragma unroll
    for (int ki = 0; ki < 4; ++ki) {
      const int sl = ki * 4 + lq;
      s16x8 a1h, a1l;
      if (GATHER) { a1h = ldf(a1p); a1l = ldf(a1p + 512); a1p += 32; }
      else        { a1h = ldl(SM, lr, sl); a1l = ldl(SM, lr, 16 + sl); }
      s16x8 a2h = ldl(SM, 64 + lr, sl), a2l = ldl(SM, 64 + lr, 16 + sl);
#pragma unroll
      for (int t = 0; t < 6; ++t) {
        s16x8 bh = ldf(bp[t]), bl = ldf(bp[t] + 512); bp[t] += 32;
        s16x8 ah = (t < 3) ? a1h : a2h;
        s16x8 al = (t < 3) ? a1l : a2l;
        acc[t] = MFMA16(ah, bh, acc[t]);
        acc[t] = MFMA16(ah, bl, acc[t]);
        acc[t] = MFMA16(al, bh, acc[t]);
      }
    }
    __syncthreads();
  }

  const int c = j0 + lrow;
  const float bir = bih[c], biz = bih[HH + c], bin = bih[2 * HH + c];
  const float bhr = bhh[c], bhz = bhh[HH + c], bhn = bhh[2 * HH + c];
  float hvv[4];
#pragma unroll
  for (int r = 0; r < 4; ++r) {
    int m = mbase + wave * 16 + lq * 4 + r;
    float ir = acc[0][r] + bir, iz = acc[1][r] + biz, inn = acc[2][r] + bin;
    float hr = acc[3][r] + bhr, hz = acc[4][r] + bhz, hn = acc[5][r] + bhn;
    float rr = sigm(ir + hr);
    float zz = sigm(iz + hz);
    float nn = tanhf(inn + rr * hn);
    float hp = COH_H ? ldf32c(&hf[(size_t)m * HH + c]) : hf[(size_t)m * HH + c];
    float hv = (1.f - zz) * nn + zz * hp;
    if (COH_H) stf32c(&hf[(size_t)m * HH + c], hv);
    else       stf32(&hf[(size_t)m * HH + c], hv);
    hvv[r] = hv;
    if (oe) oe[(size_t)m * oe_mstride + c] = f2b(hv);   // read by next kernel
  }
  __syncthreads();                      // staging buffer now dead everywhere
#pragma unroll
  for (int r = 0; r < 4; ++r) {
    const int ml = wave * 16 + lq * 4 + r;   // 0..63
    u16 hi = f2b(hvv[r]);
    SM[ml * 32 + lrow]      = hi;            // chunk overlay (4KB)
    SM[ml * 32 + 16 + lrow] = f2b(hvv[r] - b2f(hi));
  }
  __syncthreads();
  {
    u64* dst = (u64*)hs_new + (size_t)(gidx * 128 + mbase) * 8;
    const u64* src = (const u64*)SM;
    st64c(dst + tid,       src[tid]);        // full-line coalesced publish
    st64c(dst + 256 + tid, src[256 + tid]);
  }
}

// =====================================================================
// Encoder layer-0 (R8: 32 block-roles x 16 cols — keeps the serial l0
// chain short). gh via MFMA (staged split A, cached split Whh0);
// gi inline f32 (K=2, exact). R11 coalesced publish.
// =====================================================================
__device__ __forceinline__ void gru_l0_staged(
    int bx, int p, u16* SM,
    const float* __restrict__ x, const float* __restrict__ Wih0,
    const u16* __restrict__ Whh0s,
    const float* __restrict__ bih0, const float* __restrict__ bhh0,
    const u16* __restrict__ As,
    float* __restrict__ af, u16* __restrict__ as_new)
{
  const int tid  = threadIdx.x;
  const int wave = tid >> 6, lane = tid & 63;
  const int lrow = lane & 15, lq = lane >> 4;
  const int j0 = bx * 16;
  const int mw = wave * 32;
  const int r0 = mw + lrow, r1 = mw + 16 + lrow;

  const u16* bp[3];
#pragma unroll
  for (int t = 0; t < 3; ++t)
    bp[t] = Whh0s + (size_t)(t * HH + j0 + lrow) * 1024 + lq * 8;

  f32x4 acc[2][3];
#pragma unroll
  for (int i = 0; i < 2; ++i)
#pragma unroll
    for (int t = 0; t < 3; ++t) acc[i][t] = (f32x4){0.f, 0.f, 0.f, 0.f};

  for (int kc = 0; kc < 4; ++kc) {
    stage128(SM, As, kc);
    __syncthreads();
#pragma unroll
    for (int ki = 0; ki < 4; ++ki) {
      const int sl = ki * 4 + lq;
      s16x8 a0h = ldl(SM, r0, sl), a0l = ldl(SM, r0, 16 + sl);
      s16x8 a1h = ldl(SM, r1, sl), a1l = ldl(SM, r1, 16 + sl);
#pragma unroll
      for (int t = 0; t < 3; ++t) {
        s16x8 bh = ldf(bp[t]), bl = ldf(bp[t] + 512); bp[t] += 32;
        acc[0][t] = MFMA16(a0h, bh, acc[0][t]);
        acc[0][t] = MFMA16(a0h, bl, acc[0][t]);
        acc[0][t] = MFMA16(a0l, bh, acc[0][t]);
        acc[1][t] = MFMA16(a1h, bh, acc[1][t]);
        acc[1][t] = MFMA16(a1h, bl, acc[1][t]);
        acc[1][t] = MFMA16(a1l, bh, acc[1][t]);
      }
    }
    __syncthreads();
  }

  const int c = j0 + lrow;
  const float bir = bih0[c], biz = bih0[HH + c], bin = bih0[2 * HH + c];
  const float bhr = bhh0[c], bhz = bhh0[HH + c], bhn = bhh0[2 * HH + c];
  const float wr0 = Wih0[(size_t)c * 2],            wr1 = Wih0[(size_t)c * 2 + 1];
  const float wz0 = Wih0[(size_t)(HH + c) * 2],     wz1 = Wih0[(size_t)(HH + c) * 2 + 1];
  const float wn0 = Wih0[(size_t)(2 * HH + c) * 2], wn1 = Wih0[(size_t)(2 * HH + c) * 2 + 1];
  float hvv[2][4];
#pragma unroll
  for (int tm = 0; tm < 2; ++tm) {
#pragma unroll
    for (int r = 0; r < 4; ++r) {
      int m = mw + tm * 16 + lq * 4 + r;
      float x0 = x[((size_t)m * SS + p) * 2];
      float x1 = x[((size_t)m * SS + p) * 2 + 1];
      float ir  = bir + x0 * wr0 + x1 * wr1;
      float iz  = biz + x0 * wz0 + x1 * wz1;
      float inn = bin + x0 * wn0 + x1 * wn1;
      float hr = acc[tm][0][r] + bhr, hz = acc[tm][1][r] + bhz, hn = acc[tm][2][r] + bhn;
      float rr = sigm(ir + hr);
      float zz = sigm(iz + hz);
      float nn = tanhf(inn + rr * hn);
      float hp = af[(size_t)m * HH + c];      // same-thread RMW
      float hv = (1.f - zz) * nn + zz * hp;
      af[(size_t)m * HH + c] = hv;
      hvv[tm][r] = hv;
    }
  }
  __syncthreads();                      // staging buffer now dead everywhere
#pragma unroll
  for (int tm = 0; tm < 2; ++tm) {
#pragma unroll
    for (int r = 0; r < 4; ++r) {
      const int ml = mw + tm * 16 + lq * 4 + r;   // 0..127
      u16 hi = f2b(hvv[tm][r]);
      SM[ml * 32 + lrow]      = hi;               // chunk overlay (8KB)
      SM[ml * 32 + 16 + lrow] = f2b(hvv[tm][r] - b2f(hi));
    }
  }
  __syncthreads();
  {
    u64* dst = (u64*)as_new + (size_t)(bx * 128) * 8;   // group g = bx
    const u64* src = (const u64*)SM;
#pragma unroll
    for (int k = 0; k < 4; ++k)
      st64c(dst + k * 256 + tid, src[k * 256 + tid]);
  }
}

// sim[s][b] = dot(out_enc[b,s,:], n1[b,:]). b = bx>>1, s-half = bx&1.
__device__ __forceinline__ void sim_block(
    int bx, const float* __restrict__ n1f, const u16* __restrict__ oe,
    float* __restrict__ simt)
{
  const int b = bx >> 1, sc = bx & 1;
  const int wave = threadIdx.x >> 6, lane = threadIdx.x & 63;
  float xr[8];
  const u64* xp = (const u64*)(n1f + (size_t)b * HH + lane * 8);
#pragma unroll
  for (int j = 0; j < 4; ++j) {
    union { u64 q; float f[2]; } u; u.q = ld64c(xp + j);
    xr[2 * j] = u.f[0]; xr[2 * j + 1] = u.f[1];
  }
  int s0 = sc * 256 + wave * 64;
  for (int i = 0; i < 64; ++i) {
    int s = s0 + i;
    s16x8 ov = *(const s16x8*)(oe + ((size_t)b * SS + s) * HH + lane * 8);
    float acc = 0.f;
#pragma unroll
    for (int j = 0; j < 8; ++j) acc += xr[j] * b2f((u16)ov[j]);
    for (int off = 32; off; off >>= 1) acc += __shfl_down(acc, off);
    if (lane == 0) stf32c(&simt[(size_t)s * BB + b], acc);
  }
}

// Per-s softmax stats over batch dim (reference dim=0 quirk), computed ONCE.
__device__ __forceinline__ void smax_block(int bx, const float* __restrict__ simt)
{
  const int wave = threadIdx.x >> 6, lane = threadIdx.x & 63;
  const int s = bx * 4 + wave;
  union { u64 q; float f[2]; } u;
  u.q = ld64c((const u64*)&simt[(size_t)s * BB + lane * 2]);
  float mx = fmaxf(u.f[0], u.f[1]);
  for (int off = 32; off; off >>= 1) mx = fmaxf(mx, __shfl_xor(mx, off));
  float e = expf(u.f[0] - mx) + expf(u.f[1] - mx);
  for (int off = 32; off; off >>= 1) e += __shfl_xor(e, off);
  if (lane == 0) { stf32c(&g_smx[s], mx); stf32c(&g_ssum[s], e); }
}

// attention -> logits -> argmax feedback. One block per batch element.
__device__ __forceinline__ void attn_block(
    int b, int tstep, const float* __restrict__ simt, const float* __restrict__ n1f,
    const u16* __restrict__ oe, const float* __restrict__ fcW,
    const float* __restrict__ fcb, float* __restrict__ dout,
    int* __restrict__ tok)
{
  __shared__ float wsm[SS];
  __shared__ float xv[2 * HH];
  __shared__ float lg[32];
  const int t = threadIdx.x;

  for (int s = t; s < SS; s += 256) {
    float sv = ldf32c(&simt[(size_t)s * BB + b]);
    float mx = ldf32c(&g_smx[s]);
    float sm = ldf32c(&g_ssum[s]);
    wsm[s] = expf(sv - mx) / sm;
  }
  xv[t]       = ldf32c(&n1f[(size_t)b * HH + t]);
  xv[t + 256] = ldf32c(&n1f[(size_t)b * HH + t + 256]);
  __syncthreads();

  {
    float a0 = 0.f, a1 = 0.f;
    const u16* base = oe + (size_t)b * SS * HH;   // read-only: cached
    for (int s = 0; s < SS; ++s) {
      float w = wsm[s];
      a0 += w * b2f(base[(size_t)s * HH + t]);
      a1 += w * b2f(base[(size_t)s * HH + t + 256]);
    }
    xv[HH + t]       = a0;
    xv[HH + t + 256] = a1;
  }
  __syncthreads();

  int wave = t >> 6, lane = t & 63;
  for (int v = wave; v < VV; v += 4) {
    const float* wr = fcW + (size_t)v * (2 * HH);
    float acc = 0.f;
#pragma unroll
    for (int i = 0; i < 16; ++i) acc += xv[i * 64 + lane] * wr[i * 64 + lane];
    for (int off = 32; off; off >>= 1) acc += __shfl_down(acc, off);
    if (lane == 0) {
      float lv = acc + fcb[v];
      lg[v] = lv;
      dout[(size_t)b * (TT * VV) + (size_t)tstep * VV + v] = lv;  // host-read
    }
  }
  __syncthreads();

  if (t == 0) {
    float best = lg[0]; int bi = 0;
    for (int v = 1; v < VV; ++v) if (lg[v] > best) { best = lg[v]; bi = v; }
    sti32c(&tok[b], bi);
  }
}

// =====================================================================
// Persistent encoder: 96 blocks (32 l0 + 64 l1), 513 phases (R8).
// =====================================================================
__global__ __launch_bounds__(256) void enc_persist(
    const float* __restrict__ x, const float* __restrict__ Wih0,
    const u16* __restrict__ Whh0s,
    const float* __restrict__ bih0, const float* __restrict__ bhh0,
    const u16* __restrict__ Wih1s, const u16* __restrict__ Whh1s,
    const float* __restrict__ bih1, const float* __restrict__ bhh1,
    u16* ABF0, u16* ABF1, float* af,
    u16* CBF0, u16* CBF1, float* cf,
    u16* out_enc)
{
  __shared__ u16 SM[32768];
  const int bx = blockIdx.x;
  const u16* pa = ABF0; u16* pa_n = ABF1;
  const u16* pc = CBF0; u16* pc_n = CBF1;
  for (int p = 0; p <= SS; ++p) {
    waitc2(C_L0, 32 * p, C_L1, 64 * (p - 1));
    if (bx < 32) {
      if (p < SS) {
        gru_l0_staged(bx, p, SM, x, Wih0, Whh0s, bih0, bhh0, pa, af, pa_n);
        arrive(C_L0);
      }
    } else {
      if (p > 0) {
        u16* oe = out_enc + (size_t)(p - 1) * HH;
        gru_dual_staged<false, false>(bx - 32, SM, pa, nullptr, pc,
                                      Wih1s, Whh1s, bih1, bhh1,
                                      cf, pc_n, oe, (size_t)SS * HH);
        arrive(C_L1);
      }
    }
    const u16* tp;
    tp = pa; pa = pa_n; pa_n = (u16*)tp;
    tp = pc; pc = pc_n; pc_n = (u16*)tp;
  }
}

// =====================================================================
// Persistent decoder: 256 blocks, 64 steps x 5 dataflow phases (R8).
// =====================================================================
__global__ __launch_bounds__(256) void dec_persist(
    const u16* __restrict__ EMBs, int* tok,
    const u16* __restrict__ WdIH0, const u16* __restrict__ WdHH0,
    const float* __restrict__ dbih0, const float* __restrict__ dbhh0,
    const u16* __restrict__ WdIH1, const u16* __restrict__ WdHH1,
    const float* __restrict__ dbih1, const float* __restrict__ dbhh1,
    float* af, float* cf,
    u16* D0A, u16* D0B, u16* D1A, u16* D1B,
    const u16* __restrict__ oe, float* simt,
    const float* __restrict__ fcW, const float* __restrict__ fcb,
    float* dout)
{
  __shared__ u16 SM[32768];
  const int bx = blockIdx.x;
  const u16* d0c = D0A; u16* d0n = D0B;
  const u16* d1c = D1A; u16* d1n = D1B;
  for (int t = 0; t < TT; ++t) {
    if (bx < 64) {
      waitc3(C_G0, 64 * t, C_ATT, 128 * t, C_G1, 64 * (t - 1));
      gru_dual_staged<true, false>(bx, SM, EMBs, tok, d0c,
                                   WdIH0, WdHH0, dbih0, dbhh0, af, d0n,
                                   nullptr, 0);
      arrive(C_G0);
    }
    { const u16* tp = d0c; d0c = d0n; d0n = (u16*)tp; }

    if (bx < 64) {
      waitc4(C_G0, 64 * (t + 1), C_G1, 64 * t, C_SIM, 256 * t, C_ATT, 128 * t);
      gru_dual_staged<false, true>(bx, SM, d0c, nullptr, d1c,
                                   WdIH1, WdHH1, dbih1, dbhh1, cf, d1n,
                                   nullptr, 0);
      arrive(C_G1);
    }
    { const u16* tp = d1c; d1c = d1n; d1n = (u16*)tp; }

    waitc3(C_G1, 64 * (t + 1), C_SMX, 128 * t, C_ATT, 128 * t);
    sim_block(bx, cf, oe, simt);
    arrive(C_SIM);

    if (bx < 128) {
      waitc2(C_SIM, 256 * (t + 1), C_ATT, 128 * t);
      smax_block(bx, simt);
      arrive(C_SMX);
    }

    if (bx < BB) {
      waitc4(C_SMX, 128 * (t + 1), C_SIM, 256 * (t + 1),
             C_G1, 64 * (t + 1), C_G0, 64 * (t + 1));
      attn_block(bx, t, simt, cf, oe, fcW, fcb, dout, tok);
      arrive(C_ATT);
    }
  }
}

// Split weights (row-major layout: row r -> [hi x512 | lo x512]).
__global__ __launch_bounds__(256) void splitall(
    const float* __restrict__ s0, u16* d0, const float* __restrict__ s1, u16* d1,
    const float* __restrict__ s2, u16* d2, const float* __restrict__ s3, u16* d3,
    const float* __restrict__ s4, u16* d4, const float* __restrict__ s5, u16* d5,
    const float* __restrict__ s6, u16* d6, const float* __restrict__ s7, u16* d7)
{
  const int WN = 3 * HH * HH;  // 786432
  int i = blockIdx.x * 256 + threadIdx.x;
  const float* s; u16* d; int j;
  if      (i < 1 * WN) { s = s0; d = d0; j = i; }
  else if (i < 2 * WN) { s = s1; d = d1; j = i - 1 * WN; }
  else if (i < 3 * WN) { s = s2; d = d2; j = i - 2 * WN; }
  else if (i < 4 * WN) { s = s3; d = d3; j = i - 3 * WN; }
  else if (i < 5 * WN) { s = s4; d = d4; j = i - 4 * WN; }
  else if (i < 6 * WN) { s = s5; d = d5; j = i - 5 * WN; }
  else if (i < 7 * WN) { s = s6; d = d6; j = i - 6 * WN; }
  else { j = i - 7 * WN; if (j >= VV * HH) return; s = s7; d = d7; }
  int r = j >> 9, k = j & 511;
  float v = s[j];
  u16 hi = f2b(v);
  d[(size_t)r * 1024 + k]       = hi;
  d[(size_t)r * 1024 + 512 + k] = f2b(v - b2f(hi));
}

__global__ __launch_bounds__(256) void initk(
    float* af, float* cf, u16* b0, u16* b1, u16* b2, u16* b3, int* tok)
{
  int i = blockIdx.x * 256 + threadIdx.x;   // 131072 threads
  b0[i] = 0; b1[i] = 0; b2[i] = 0; b3[i] = 0;
  if (i < BB * HH) { af[i] = 0.f; cf[i] = 0.f; }
  if (i < BB) tok[i] = 0;
  if (i < 128) g_cnt[i] = 0;
}

__global__ __launch_bounds__(256) void finalize(
    const float* __restrict__ d0, const float* __restrict__ d1,
    float* __restrict__ oh)
{
  int i = blockIdx.x * 256 + threadIdx.x;
  oh[i]           = d0[i];
  oh[BB * HH + i] = d1[i];
}

extern "C" void kernel_launch(void* const* d_in, const int* in_sizes, int n_in,
                              void* d_out, int out_size, void* d_ws, size_t ws_size,
                              hipStream_t stream) {
  const float* x     = (const float*)d_in[0];
  const float* emb   = (const float*)d_in[1];
  const float* eWih0 = (const float*)d_in[2];
  const float* eWhh0 = (const float*)d_in[3];
  const float* ebih0 = (const float*)d_in[4];
  const float* ebhh0 = (const float*)d_in[5];
  const float* eWih1 = (const float*)d_in[6];
  const float* eWhh1 = (const float*)d_in[7];
  const float* ebih1 = (const float*)d_in[8];
  const float* ebhh1 = (const float*)d_in[9];
  const float* dWih0 = (const float*)d_in[10];
  const float* dWhh0 = (const float*)d_in[11];
  const float* dbih0 = (const float*)d_in[12];
  const float* dbhh0 = (const float*)d_in[13];
  const float* dWih1 = (const float*)d_in[14];
  const float* dWhh1 = (const float*)d_in[15];
  const float* dbih1 = (const float*)d_in[16];
  const float* dbhh1 = (const float*)d_in[17];
  const float* fcW   = (const float*)d_in[18];
  const float* fcb   = (const float*)d_in[19];
  float* dout = (float*)d_out;

  char* wsb = (char*)d_ws;
  float* af   = (float*)(wsb + 0);          // 128x512 f32 (a / d0 state, RMW)
  float* cf   = (float*)(wsb + 262144);     // 128x512 f32 (c / d1 state, RMW)
  u16* ABF0   = (u16*)(wsb + 524288);       // SBUF-layout states, 256KB each
  u16* ABF1   = (u16*)(wsb + 786432);
  u16* CBF0   = (u16*)(wsb + 1048576);
  u16* CBF1   = (u16*)(wsb + 1310720);
  int* tok    = (int*)(wsb + 1572864);
  float* simt = (float*)(wsb + 1573376);    // [S][B] f32, 256 KB
  u16* WeHH0  = (u16*)(wsb + 1835520);      // split weights, 3 MB each
  u16* WeIH1  = (u16*)(wsb + 4981248);
  u16* WeHH1  = (u16*)(wsb + 8126976);
  u16* WdIH0  = (u16*)(wsb + 11272704);
  u16* WdHH0  = (u16*)(wsb + 14418432);
  u16* WdIH1  = (u16*)(wsb + 17564160);
  u16* WdHH1  = (u16*)(wsb + 20709888);
  u16* EMBs   = (u16*)(wsb + 23855616);     // 30x1024 u16, row-major layout
  u16* oe     = (u16*)(wsb + 23917056);     // out_enc bf16 [B][S][H], 64 MiB

  initk<<<512, 256, 0, stream>>>(af, cf, ABF0, ABF1, CBF0, CBF1, tok);

  splitall<<<21564, 256, 0, stream>>>(eWhh0, WeHH0, eWih1, WeIH1, eWhh1, WeHH1,
                                      dWih0, WdIH0, dWhh0, WdHH0, dWih1, WdIH1,
                                      dWhh1, WdHH1, emb, EMBs);

  enc_persist<<<96, 256, 0, stream>>>(x, eWih0, WeHH0, ebih0, ebhh0,
                                      WeIH1, WeHH1, ebih1, ebhh1,
                                      ABF0, ABF1, af, CBF0, CBF1, cf, oe);

  // a_511 SBUF in ABF0 (written p=511); c_511 SBUF in CBF1 (written p=512)
  dec_persist<<<256, 256, 0, stream>>>(EMBs, tok, WdIH0, WdHH0, dbih0, dbhh0,
                                       WdIH1, WdHH1, dbih1, dbhh1,
                                       af, cf, ABF0, ABF1, CBF1, CBF0,
                                       oe, simt, fcW, fcb, dout);

  finalize<<<256, 256, 0, stream>>>(af, cf, dout + (size_t)BB * TT * VV);
}

// Round 12
// 24009.709 us; speedup vs baseline: 1.5409x; 1.0637x over previous
//
#include <hip/hip_runtime.h>
#include <math.h>

typedef short  s16x8 __attribute__((ext_vector_type(8)));
typedef float  f32x4 __attribute__((ext_vector_type(4)));
typedef unsigned short u16;
typedef unsigned long long u64;

#define MFMA16(a, b, c) __builtin_amdgcn_mfma_f32_16x16x32_bf16((a), (b), (c), 0, 0, 0)

#define BB 128
#define SS 512
#define HH 512
#define VV 30
#define TT 64

#define SC_SYS  __HIP_MEMORY_SCOPE_SYSTEM

__device__ __forceinline__ float b2f(u16 v) {
  union { unsigned int u; float f; } c; c.u = ((unsigned int)v) << 16; return c.f;
}
__device__ __forceinline__ u16 f2b(float f) {
  union { float f; unsigned int u; } c; c.f = f;
  unsigned int r = (c.u + 0x7FFFu + ((c.u >> 16) & 1u)) >> 16;
  return (u16)r;
}
__device__ __forceinline__ float sigm(float x) { return 1.f / (1.f + expf(-x)); }
__device__ __forceinline__ s16x8 ldf(const u16* p) { return *(const s16x8*)p; }

// ---- coherent (MALL-level) helpers for cross-block data ----
__device__ __forceinline__ u64  ld64c(const u64* p)      { return __hip_atomic_load(p, __ATOMIC_RELAXED, SC_SYS); }
__device__ __forceinline__ void st64c(u64* p, u64 v)     { __hip_atomic_store(p, v, __ATOMIC_RELAXED, SC_SYS); }
__device__ __forceinline__ void stf32c(float* p, float v){ __hip_atomic_store(p, v, __ATOMIC_RELAXED, SC_SYS); }
__device__ __forceinline__ float ldf32c(const float* p)  { return __hip_atomic_load(p, __ATOMIC_RELAXED, SC_SYS); }
__device__ __forceinline__ void sti32c(int* p, int v)    { __hip_atomic_store(p, v, __ATOMIC_RELAXED, SC_SYS); }
__device__ __forceinline__ int  ldi32c(const int* p)     { return __hip_atomic_load(p, __ATOMIC_RELAXED, SC_SYS); }
__device__ __forceinline__ void stf32(float* p, float v) { *p = v; }

// ---------------------------------------------------------------------
// R12 distributed dataflow sync. R3..R11 all converged every phase via
// atomicAdd on ONE MALL line + ~96 thread0s polling that SAME line —
// far-atomic RMWs to one address serialize and the poll storm contends
// with them (~10-20us/phase, the invariant cost across all designs).
// Now: each block owns a PADDED SLOT (64B line); arrival = one plain
// system store (no RMW). Waiting block polls producer slots IN PARALLEL
// (thread t polls slot t), then one __syncthreads.
// Visibility: each wave's sc data stores are vmcnt-drained by the
// __syncthreads before the slot store (compiler emits vmcnt(0) before
// s_barrier), so slot>=target => producer data MALL-visible.
// Wait targets = transitive reduction of the R8-verified dep graph.
// ---------------------------------------------------------------------
__device__ unsigned int g_slot[736 * 16];   // slot i lives at g_slot[i*16]
__device__ float g_smx[SS], g_ssum[SS];

#define S_L0  0     // 32 slots (enc layer0)
#define S_L1  32    // 64 slots (enc layer1)
#define S_G0  96    // 64 slots (dec gru0)
#define S_G1  160   // 64 slots (dec gru1)
#define S_SIM 224   // 256 slots
#define S_SMX 480   // 128 slots
#define S_ATT 608   // 128 slots  (total 736)

__device__ __forceinline__ void pollslot(int idx, int target) {
  if (target <= 0) return;
  const unsigned int* p = &g_slot[idx * 16];
  unsigned long long t0 = __builtin_amdgcn_s_memrealtime();
  while ((int)__hip_atomic_load(p, __ATOMIC_RELAXED, SC_SYS) < target) {
    __builtin_amdgcn_s_sleep(1);
    if (__builtin_amdgcn_s_memrealtime() - t0 > (1ull << 21)) break;
  }
}
// all threads: parallel poll of one producer group, then join
__device__ __forceinline__ void wait_group(int base, int n, int target) {
  if ((int)threadIdx.x < n) pollslot(base + (int)threadIdx.x, target);
  __syncthreads();
}
// enc wait: L0 >= p (32 slots) AND L1 >= p-1 (64 slots), polled in parallel
__device__ __forceinline__ void enc_wait(int p) {
  const int t = threadIdx.x;
  if (t < 32) pollslot(S_L0 + t, p);
  else if (t < 96) pollslot(S_L1 + (t - 32), p - 1);
  __syncthreads();
}
// arrival: block's data stores drained by __syncthreads, then own-slot store
__device__ __forceinline__ void postslot(int idx, int val) {
  __syncthreads();
  if (threadIdx.x == 0)
    __hip_atomic_store(&g_slot[idx * 16], (unsigned int)val, __ATOMIC_RELAXED, SC_SYS);
}

// ---------------------------------------------------------------------
// State buffers: chunked SBUF layout u16 SBUF[32][128][32] (verified R8).
// Chunk (g,m) = one 64B line: u16 0..15 = hi of cols [16g,16g+16),
// 16..31 = lo. Consumers stage linearly; producers publish full lines
// via LDS transpose (R11). LDS per buffer: 128 rows x 512B; slot s of
// row at (s ^ (row&15)).
// ---------------------------------------------------------------------
__device__ __forceinline__ s16x8 ldl(const u16* buf, int row, int slot) {
  return *(const s16x8*)&buf[(row << 8) + ((slot ^ (row & 15)) << 3)];
}

// Stage 64 rows (mbase..mbase+63) of one SBUF source for K-chunk kc.
__device__ __forceinline__ void stage64(u16* SMb, const u16* SRC, int mbase, int kc) {
  const int t = threadIdx.x;
  const u64* base = (const u64*)SRC;
  u64 v[16];
#pragma unroll
  for (int j = 0; j < 16; ++j) {
    const int g = kc * 8 + (j >> 1);
    const int half = j & 1;
    v[j] = ld64c(base + (size_t)(g * 128 + mbase + half * 32) * 8 + t);
  }
#pragma unroll
  for (int j = 0; j < 16; ++j) {
    const int gl = j >> 1, half = j & 1;
    const int row = half * 32 + (t >> 3);
    const int w = t & 7;
    const int s = ((w & 4) << 2) + 2 * gl + ((w >> 1) & 1);
    *(u64*)&SMb[(row << 8) + ((s ^ (row & 15)) << 3) + ((w & 1) << 2)] = v[j];
  }
}

// Stage all 128 rows (enc-l0) for K-chunk kc.
__device__ __forceinline__ void stage128(u16* SM, const u16* SRC, int kc) {
  const int t = threadIdx.x;
  const u64* base = (const u64*)SRC;
  u64 v[32];
#pragma unroll
  for (int j = 0; j < 32; ++j) {
    const int g = kc * 8 + (j >> 2);
    const int q = j & 3;
    v[j] = ld64c(base + (size_t)(g * 128 + q * 32) * 8 + t);
  }
#pragma unroll
  for (int j = 0; j < 32; ++j) {
    const int gl = j >> 2, q = j & 3;
    const int row = q * 32 + (t >> 3);
    const int w = t & 7;
    const int s = ((w & 4) << 2) + 2 * gl + ((w >> 1) & 1);
    *(u64*)&SM[(row << 8) + ((s ^ (row & 15)) << 3) + ((w & 1) << 2)] = v[j];
  }
}

// Split-f32 format per logical row of K=512: hi = bf16(v), lo = bf16(v-hi).
// GEMM does hi*hi + hi*lo + lo*hi (Markidis).

// =====================================================================
// Dual-input GRU cell (enc-l1 / decoder): 64 block-roles x 256 thr.
// R8 staging/MFMA; R11 coalesced publish.
// =====================================================================
template <bool GATHER, bool COH_H>
__device__ __forceinline__ void gru_dual_staged(
    int bx, u16* SM,
    const u16* __restrict__ A1s, const int* __restrict__ gather,
    const u16* __restrict__ A2s,
    const u16* __restrict__ Wihs, const u16* __restrict__ Whhs,
    const float* __restrict__ bih, const float* __restrict__ bhh,
    float* __restrict__ hf, u16* __restrict__ hs_new,
    u16* __restrict__ oe, size_t oe_mstride)
{
  const int tid  = threadIdx.x;
  const int wave = tid >> 6, lane = tid & 63;
  const int lrow = lane & 15, lq = lane >> 4;
  const int gidx = bx >> 1;             // 16-col group
  const int j0 = gidx * 16;
  const int mbase = (bx & 1) * 64;
  const int lr = wave * 16 + lrow;      // local row 0..63
  const int m0 = mbase + wave * 16;

  const u16* a1p = nullptr;
  if (GATHER)
    a1p = A1s + (size_t)ldi32c(&gather[m0 + lrow]) * 1024 + lq * 8;

  const u16* bp[6];
#pragma unroll
  for (int t = 0; t < 6; ++t) {
    int g = (t < 3) ? t : t - 3;
    const u16* W = (t < 3) ? Wihs : Whhs;
    bp[t] = W + (size_t)(g * HH + j0 + lrow) * 1024 + lq * 8;
  }

  f32x4 acc[6];
#pragma unroll
  for (int t = 0; t < 6; ++t) acc[t] = (f32x4){0.f, 0.f, 0.f, 0.f};

  for (int kc = 0; kc < 4; ++kc) {
    if (!GATHER) stage64(SM, A1s, mbase, kc);
    stage64(SM + 64 * 256, A2s, mbase, kc);
    __syncthreads();
#pragma unroll
    for (int ki = 0; ki < 4; ++ki) {
      const int sl = ki * 4 + lq;
      s16x8 a1h, a1l;
      if (GATHER) { a1h = ldf(a1p); a1l = ldf(a1p + 512); a1p += 32; }
      else        { a1h = ldl(SM, lr, sl); a1l = ldl(SM, lr, 16 + sl); }
      s16x8 a2h = ldl(SM, 64 + lr, sl), a2l = ldl(SM, 64 + lr, 16 + sl);
#pragma unroll
      for (int t = 0; t < 6; ++t) {
        s16x8 bh = ldf(bp[t]), bl = ldf(bp[t] + 512); bp[t] += 32;
        s16x8 ah = (t < 3) ? a1h : a2h;
        s16x8 al = (t < 3) ? a1l : a2l;
        acc[t] = MFMA16(ah, bh, acc[t]);
        acc[t] = MFMA16(ah, bl, acc[t]);
        acc[t] = MFMA16(al, bh, acc[t]);
      }
    }
    __syncthreads();
  }

  const int c = j0 + lrow;
  const float bir = bih[c], biz = bih[HH + c], bin = bih[2 * HH + c];
  const float bhr = bhh[c], bhz = bhh[HH + c], bhn = bhh[2 * HH + c];
  float hvv[4];
#pragma unroll
  for (int r = 0; r < 4; ++r) {
    int m = mbase + wave * 16 + lq * 4 + r;
    float ir = acc[0][r] + bir, iz = acc[1][r] + biz, inn = acc[2][r] + bin;
    float hr = acc[3][r] + bhr, hz = acc[4][r] + bhz, hn = acc[5][r] + bhn;
    float rr = sigm(ir + hr);
    float zz = sigm(iz + hz);
    float nn = tanhf(inn + rr * hn);
    float hp = COH_H ? ldf32c(&hf[(size_t)m * HH + c]) : hf[(size_t)m * HH + c];
    float hv = (1.f - zz) * nn + zz * hp;
    if (COH_H) stf32c(&hf[(size_t)m * HH + c], hv);
    else       stf32(&hf[(size_t)m * HH + c], hv);
    hvv[r] = hv;
    if (oe) oe[(size_t)m * oe_mstride + c] = f2b(hv);   // read by next kernel
  }
  __syncthreads();                      // staging buffer now dead everywhere
#pragma unroll
  for (int r = 0; r < 4; ++r) {
    const int ml = wave * 16 + lq * 4 + r;   // 0..63
    u16 hi = f2b(hvv[r]);
    SM[ml * 32 + lrow]      = hi;            // chunk overlay (4KB)
    SM[ml * 32 + 16 + lrow] = f2b(hvv[r] - b2f(hi));
  }
  __syncthreads();
  {
    u64* dst = (u64*)hs_new + (size_t)(gidx * 128 + mbase) * 8;
    const u64* src = (const u64*)SM;
    st64c(dst + tid,       src[tid]);        // full-line coalesced publish
    st64c(dst + 256 + tid, src[256 + tid]);
  }
}

// =====================================================================
// Encoder layer-0 (32 block-roles x 16 cols). gh via MFMA (staged split
// A, cached split Whh0); gi inline f32 (K=2, exact). R11 publish.
// =====================================================================
__device__ __forceinline__ void gru_l0_staged(
    int bx, int p, u16* SM,
    const float* __restrict__ x, const float* __restrict__ Wih0,
    const u16* __restrict__ Whh0s,
    const float* __restrict__ bih0, const float* __restrict__ bhh0,
    const u16* __restrict__ As,
    float* __restrict__ af, u16* __restrict__ as_new)
{
  const int tid  = threadIdx.x;
  const int wave = tid >> 6, lane = tid & 63;
  const int lrow = lane & 15, lq = lane >> 4;
  const int j0 = bx * 16;
  const int mw = wave * 32;
  const int r0 = mw + lrow, r1 = mw + 16 + lrow;

  const u16* bp[3];
#pragma unroll
  for (int t = 0; t < 3; ++t)
    bp[t] = Whh0s + (size_t)(t * HH + j0 + lrow) * 1024 + lq * 8;

  f32x4 acc[2][3];
#pragma unroll
  for (int i = 0; i < 2; ++i)
#pragma unroll
    for (int t = 0; t < 3; ++t) acc[i][t] = (f32x4){0.f, 0.f, 0.f, 0.f};

  for (int kc = 0; kc < 4; ++kc) {
    stage128(SM, As, kc);
    __syncthreads();
#pragma unroll
    for (int ki = 0; ki < 4; ++ki) {
      const int sl = ki * 4 + lq;
      s16x8 a0h = ldl(SM, r0, sl), a0l = ldl(SM, r0, 16 + sl);
      s16x8 a1h = ldl(SM, r1, sl), a1l = ldl(SM, r1, 16 + sl);
#pragma unroll
      for (int t = 0; t < 3; ++t) {
        s16x8 bh = ldf(bp[t]), bl = ldf(bp[t] + 512); bp[t] += 32;
        acc[0][t] = MFMA16(a0h, bh, acc[0][t]);
        acc[0][t] = MFMA16(a0h, bl, acc[0][t]);
        acc[0][t] = MFMA16(a0l, bh, acc[0][t]);
        acc[1][t] = MFMA16(a1h, bh, acc[1][t]);
        acc[1][t] = MFMA16(a1h, bl, acc[1][t]);
        acc[1][t] = MFMA16(a1l, bh, acc[1][t]);
      }
    }
    __syncthreads();
  }

  const int c = j0 + lrow;
  const float bir = bih0[c], biz = bih0[HH + c], bin = bih0[2 * HH + c];
  const float bhr = bhh0[c], bhz = bhh0[HH + c], bhn = bhh0[2 * HH + c];
  const float wr0 = Wih0[(size_t)c * 2],            wr1 = Wih0[(size_t)c * 2 + 1];
  const float wz0 = Wih0[(size_t)(HH + c) * 2],     wz1 = Wih0[(size_t)(HH + c) * 2 + 1];
  const float wn0 = Wih0[(size_t)(2 * HH + c) * 2], wn1 = Wih0[(size_t)(2 * HH + c) * 2 + 1];
  float hvv[2][4];
#pragma unroll
  for (int tm = 0; tm < 2; ++tm) {
#pragma unroll
    for (int r = 0; r < 4; ++r) {
      int m = mw + tm * 16 + lq * 4 + r;
      float x0 = x[((size_t)m * SS + p) * 2];
      float x1 = x[((size_t)m * SS + p) * 2 + 1];
      float ir  = bir + x0 * wr0 + x1 * wr1;
      float iz  = biz + x0 * wz0 + x1 * wz1;
      float inn = bin + x0 * wn0 + x1 * wn1;
      float hr = acc[tm][0][r] + bhr, hz = acc[tm][1][r] + bhz, hn = acc[tm][2][r] + bhn;
      float rr = sigm(ir + hr);
      float zz = sigm(iz + hz);
      float nn = tanhf(inn + rr * hn);
      float hp = af[(size_t)m * HH + c];      // same-thread RMW
      float hv = (1.f - zz) * nn + zz * hp;
      af[(size_t)m * HH + c] = hv;
      hvv[tm][r] = hv;
    }
  }
  __syncthreads();                      // staging buffer now dead everywhere
#pragma unroll
  for (int tm = 0; tm < 2; ++tm) {
#pragma unroll
    for (int r = 0; r < 4; ++r) {
      const int ml = mw + tm * 16 + lq * 4 + r;   // 0..127
      u16 hi = f2b(hvv[tm][r]);
      SM[ml * 32 + lrow]      = hi;               // chunk overlay (8KB)
      SM[ml * 32 + 16 + lrow] = f2b(hvv[tm][r] - b2f(hi));
    }
  }
  __syncthreads();
  {
    u64* dst = (u64*)as_new + (size_t)(bx * 128) * 8;   // group g = bx
    const u64* src = (const u64*)SM;
#pragma unroll
    for (int k = 0; k < 4; ++k)
      st64c(dst + k * 256 + tid, src[k * 256 + tid]);
  }
}

// sim[s][b] = dot(out_enc[b,s,:], n1[b,:]). b = bx>>1, s-half = bx&1.
__device__ __forceinline__ void sim_block(
    int bx, const float* __restrict__ n1f, const u16* __restrict__ oe,
    float* __restrict__ simt)
{
  const int b = bx >> 1, sc = bx & 1;
  const int wave = threadIdx.x >> 6, lane = threadIdx.x & 63;
  float xr[8];
  const u64* xp = (const u64*)(n1f + (size_t)b * HH + lane * 8);
#pragma unroll
  for (int j = 0; j < 4; ++j) {
    union { u64 q; float f[2]; } u; u.q = ld64c(xp + j);
    xr[2 * j] = u.f[0]; xr[2 * j + 1] = u.f[1];
  }
  int s0 = sc * 256 + wave * 64;
  for (int i = 0; i < 64; ++i) {
    int s = s0 + i;
    s16x8 ov = *(const s16x8*)(oe + ((size_t)b * SS + s) * HH + lane * 8);
    float acc = 0.f;
#pragma unroll
    for (int j = 0; j < 8; ++j) acc += xr[j] * b2f((u16)ov[j]);
    for (int off = 32; off; off >>= 1) acc += __shfl_down(acc, off);
    if (lane == 0) stf32c(&simt[(size_t)s * BB + b], acc);
  }
}

// Per-s softmax stats over batch dim (reference dim=0 quirk), computed ONCE.
__device__ __forceinline__ void smax_block(int bx, const float* __restrict__ simt)
{
  const int wave = threadIdx.x >> 6, lane = threadIdx.x & 63;
  const int s = bx * 4 + wave;
  union { u64 q; float f[2]; } u;
  u.q = ld64c((const u64*)&simt[(size_t)s * BB + lane * 2]);
  float mx = fmaxf(u.f[0], u.f[1]);
  for (int off = 32; off; off >>= 1) mx = fmaxf(mx, __shfl_xor(mx, off));
  float e = expf(u.f[0] - mx) + expf(u.f[1] - mx);
  for (int off = 32; off; off >>= 1) e += __shfl_xor(e, off);
  if (lane == 0) { stf32c(&g_smx[s], mx); stf32c(&g_ssum[s], e); }
}

// attention -> logits -> argmax feedback. One block per batch element.
__device__ __forceinline__ void attn_block(
    int b, int tstep, const float* __restrict__ simt, const float* __restrict__ n1f,
    const u16* __restrict__ oe, const float* __restrict__ fcW,
    const float* __restrict__ fcb, float* __restrict__ dout,
    int* __restrict__ tok)
{
  __shared__ float wsm[SS];
  __shared__ float xv[2 * HH];
  __shared__ float lg[32];
  const int t = threadIdx.x;

  for (int s = t; s < SS; s += 256) {
    float sv = ldf32c(&simt[(size_t)s * BB + b]);
    float mx = ldf32c(&g_smx[s]);
    float sm = ldf32c(&g_ssum[s]);
    wsm[s] = expf(sv - mx) / sm;
  }
  xv[t]       = ldf32c(&n1f[(size_t)b * HH + t]);
  xv[t + 256] = ldf32c(&n1f[(size_t)b * HH + t + 256]);
  __syncthreads();

  {
    float a0 = 0.f, a1 = 0.f;
    const u16* base = oe + (size_t)b * SS * HH;   // read-only: cached
    for (int s = 0; s < SS; ++s) {
      float w = wsm[s];
      a0 += w * b2f(base[(size_t)s * HH + t]);
      a1 += w * b2f(base[(size_t)s * HH + t + 256]);
    }
    xv[HH + t]       = a0;
    xv[HH + t + 256] = a1;
  }
  __syncthreads();

  int wave = t >> 6, lane = t & 63;
  for (int v = wave; v < VV; v += 4) {
    const float* wr = fcW + (size_t)v * (2 * HH);
    float acc = 0.f;
#pragma unroll
    for (int i = 0; i < 16; ++i) acc += xv[i * 64 + lane] * wr[i * 64 + lane];
    for (int off = 32; off; off >>= 1) acc += __shfl_down(acc, off);
    if (lane == 0) {
      float lv = acc + fcb[v];
      lg[v] = lv;
      dout[(size_t)b * (TT * VV) + (size_t)tstep * VV + v] = lv;  // host-read
    }
  }
  __syncthreads();

  if (t == 0) {
    float best = lg[0]; int bi = 0;
    for (int v = 1; v < VV; ++v) if (lg[v] > best) { best = lg[v]; bi = v; }
    sti32c(&tok[b], bi);
  }
}

// =====================================================================
// Persistent encoder: 96 blocks (32 l0 + 64 l1), 513 phases.
// Waits: L0 >= p (full a_{p-1}) and L1 >= p-1 (buffer free / c_{p-1}).
// Arrivals: own slot only (l0 stores p+1, l1 stores p).
// =====================================================================
__global__ __launch_bounds__(256) void enc_persist(
    const float* __restrict__ x, const float* __restrict__ Wih0,
    const u16* __restrict__ Whh0s,
    const float* __restrict__ bih0, const float* __restrict__ bhh0,
    const u16* __restrict__ Wih1s, const u16* __restrict__ Whh1s,
    const float* __restrict__ bih1, const float* __restrict__ bhh1,
    u16* ABF0, u16* ABF1, float* af,
    u16* CBF0, u16* CBF1, float* cf,
    u16* out_enc)
{
  __shared__ u16 SM[32768];
  const int bx = blockIdx.x;
  const u16* pa = ABF0; u16* pa_n = ABF1;
  const u16* pc = CBF0; u16* pc_n = CBF1;
  for (int p = 0; p <= SS; ++p) {
    enc_wait(p);
    if (bx < 32) {
      if (p < SS) {
        gru_l0_staged(bx, p, SM, x, Wih0, Whh0s, bih0, bhh0, pa, af, pa_n);
        postslot(S_L0 + bx, p + 1);
      }
    } else {
      if (p > 0) {
        u16* oe = out_enc + (size_t)(p - 1) * HH;
        gru_dual_staged<false, false>(bx - 32, SM, pa, nullptr, pc,
                                      Wih1s, Whh1s, bih1, bhh1,
                                      cf, pc_n, oe, (size_t)SS * HH);
        postslot(S_L1 + (bx - 32), p);
      }
    }
    const u16* tp;
    tp = pa; pa = pa_n; pa_n = (u16*)tp;
    tp = pc; pc = pc_n; pc_n = (u16*)tp;
  }
}

// =====================================================================
// Persistent decoder: 256 blocks, 64 steps x 5 phases. Transitively
// reduced waits: G0<-ATT>=t, G1<-G0>=t+1, SIM<-G1>=t+1, SMX<-SIM>=t+1,
// ATT<-SMX>=t+1 (each implies all of R8's explicit multi-way waits).
// =====================================================================
__global__ __launch_bounds__(256) void dec_persist(
    const u16* __restrict__ EMBs, int* tok,
    const u16* __restrict__ WdIH0, const u16* __restrict__ WdHH0,
    const float* __restrict__ dbih0, const float* __restrict__ dbhh0,
    const u16* __restrict__ WdIH1, const u16* __restrict__ WdHH1,
    const float* __restrict__ dbih1, const float* __restrict__ dbhh1,
    float* af, float* cf,
    u16* D0A, u16* D0B, u16* D1A, u16* D1B,
    const u16* __restrict__ oe, float* simt,
    const float* __restrict__ fcW, const float* __restrict__ fcb,
    float* dout)
{
  __shared__ u16 SM[32768];
  const int bx = blockIdx.x;
  const u16* d0c = D0A; u16* d0n = D0B;
  const u16* d1c = D1A; u16* d1n = D1B;
  for (int t = 0; t < TT; ++t) {
    if (bx < 64) {
      wait_group(S_ATT, 128, t);        // implies G1>=t, G0>=t, SIM>=t, SMX>=t
      gru_dual_staged<true, false>(bx, SM, EMBs, tok, d0c,
                                   WdIH0, WdHH0, dbih0, dbhh0, af, d0n,
                                   nullptr, 0);
      postslot(S_G0 + bx, t + 1);
    }
    { const u16* tp = d0c; d0c = d0n; d0n = (u16*)tp; }

    if (bx < 64) {
      wait_group(S_G0, 64, t + 1);      // full d0_t ready (implies rest)
      gru_dual_staged<false, true>(bx, SM, d0c, nullptr, d1c,
                                   WdIH1, WdHH1, dbih1, dbhh1, cf, d1n,
                                   nullptr, 0);
      postslot(S_G1 + bx, t + 1);
    }
    { const u16* tp = d1c; d1c = d1n; d1n = (u16*)tp; }

    wait_group(S_G1, 64, t + 1);        // cf_t ready (implies rest)
    sim_block(bx, cf, oe, simt);
    postslot(S_SIM + bx, t + 1);

    if (bx < 128) {
      wait_group(S_SIM, 256, t + 1);    // simt_t ready (implies rest)
      smax_block(bx, simt);
      postslot(S_SMX + bx, t + 1);
    }

    if (bx < BB) {
      wait_group(S_SMX, 128, t + 1);    // stats ready (implies rest)
      attn_block(bx, t, simt, cf, oe, fcW, fcb, dout, tok);
      postslot(S_ATT + bx, t + 1);
    }
  }
}

// Split weights (row-major layout: row r -> [hi x512 | lo x512]).
__global__ __launch_bounds__(256) void splitall(
    const float* __restrict__ s0, u16* d0, const float* __restrict__ s1, u16* d1,
    const float* __restrict__ s2, u16* d2, const float* __restrict__ s3, u16* d3,
    const float* __restrict__ s4, u16* d4, const float* __restrict__ s5, u16* d5,
    const float* __restrict__ s6, u16* d6, const float* __restrict__ s7, u16* d7)
{
  const int WN = 3 * HH * HH;  // 786432
  int i = blockIdx.x * 256 + threadIdx.x;
  const float* s; u16* d; int j;
  if      (i < 1 * WN) { s = s0; d = d0; j = i; }
  else if (i < 2 * WN) { s = s1; d = d1; j = i - 1 * WN; }
  else if (i < 3 * WN) { s = s2; d = d2; j = i - 2 * WN; }
  else if (i < 4 * WN) { s = s3; d = d3; j = i - 3 * WN; }
  else if (i < 5 * WN) { s = s4; d = d4; j = i - 4 * WN; }
  else if (i < 6 * WN) { s = s5; d = d5; j = i - 5 * WN; }
  else if (i < 7 * WN) { s = s6; d = d6; j = i - 6 * WN; }
  else { j = i - 7 * WN; if (j >= VV * HH) return; s = s7; d = d7; }
  int r = j >> 9, k = j & 511;
  float v = s[j];
  u16 hi = f2b(v);
  d[(size_t)r * 1024 + k]       = hi;
  d[(size_t)r * 1024 + 512 + k] = f2b(v - b2f(hi));
}

__global__ __launch_bounds__(256) void initk(
    float* af, float* cf, u16* b0, u16* b1, u16* b2, u16* b3, int* tok)
{
  int i = blockIdx.x * 256 + threadIdx.x;   // 131072 threads
  b0[i] = 0; b1[i] = 0; b2[i] = 0; b3[i] = 0;
  if (i < BB * HH) { af[i] = 0.f; cf[i] = 0.f; }
  if (i < BB) tok[i] = 0;
  if (i < 736) g_slot[i * 16] = 0;
}

__global__ __launch_bounds__(256) void finalize(
    const float* __restrict__ d0, const float* __restrict__ d1,
    float* __restrict__ oh)
{
  int i = blockIdx.x * 256 + threadIdx.x;
  oh[i]           = d0[i];
  oh[BB * HH + i] = d1[i];
}

extern "C" void kernel_launch(void* const* d_in, const int* in_sizes, int n_in,
                              void* d_out, int out_size, void* d_ws, size_t ws_size,
                              hipStream_t stream) {
  const float* x     = (const float*)d_in[0];
  const float* emb   = (const float*)d_in[1];
  const float* eWih0 = (const float*)d_in[2];
  const float* eWhh0 = (const float*)d_in[3];
  const float* ebih0 = (const float*)d_in[4];
  const float* ebhh0 = (const float*)d_in[5];
  const float* eWih1 = (const float*)d_in[6];
  const float* eWhh1 = (const float*)d_in[7];
  const float* ebih1 = (const float*)d_in[8];
  const float* ebhh1 = (const float*)d_in[9];
  const float* dWih0 = (const float*)d_in[10];
  const float* dWhh0 = (const float*)d_in[11];
  const float* dbih0 = (const float*)d_in[12];
  const float* dbhh0 = (const float*)d_in[13];
  const float* dWih1 = (const float*)d_in[14];
  const float* dWhh1 = (const float*)d_in[15];
  const float* dbih1 = (const float*)d_in[16];
  const float* dbhh1 = (const float*)d_in[17];
  const float* fcW   = (const float*)d_in[18];
  const float* fcb   = (const float*)d_in[19];
  float* dout = (float*)d_out;

  char* wsb = (char*)d_ws;
  float* af   = (float*)(wsb + 0);          // 128x512 f32 (a / d0 state, RMW)
  float* cf   = (float*)(wsb + 262144);     // 128x512 f32 (c / d1 state, RMW)
  u16* ABF0   = (u16*)(wsb + 524288);       // SBUF-layout states, 256KB each
  u16* ABF1   = (u16*)(wsb + 786432);
  u16* CBF0   = (u16*)(wsb + 1048576);
  u16* CBF1   = (u16*)(wsb + 1310720);
  int* tok    = (int*)(wsb + 1572864);
  float* simt = (float*)(wsb + 1573376);    // [S][B] f32, 256 KB
  u16* WeHH0  = (u16*)(wsb + 1835520);      // split weights, 3 MB each
  u16* WeIH1  = (u16*)(wsb + 4981248);
  u16* WeHH1  = (u16*)(wsb + 8126976);
  u16* WdIH0  = (u16*)(wsb + 11272704);
  u16* WdHH0  = (u16*)(wsb + 14418432);
  u16* WdIH1  = (u16*)(wsb + 17564160);
  u16* WdHH1  = (u16*)(wsb + 20709888);
  u16* EMBs   = (u16*)(wsb + 23855616);     // 30x1024 u16, row-major layout
  u16* oe     = (u16*)(wsb + 23917056);     // out_enc bf16 [B][S][H], 64 MiB

  initk<<<512, 256, 0, stream>>>(af, cf, ABF0, ABF1, CBF0, CBF1, tok);

  splitall<<<21564, 256, 0, stream>>>(eWhh0, WeHH0, eWih1, WeIH1, eWhh1, WeHH1,
                                      dWih0, WdIH0, dWhh0, WdHH0, dWih1, WdIH1,
                                      dWhh1, WdHH1, emb, EMBs);

  enc_persist<<<96, 256, 0, stream>>>(x, eWih0, WeHH0, ebih0, ebhh0,
                                      WeIH1, WeHH1, ebih1, ebhh1,
                                      ABF0, ABF1, af, CBF0, CBF1, cf, oe);

  // a_511 SBUF in ABF0 (written p=511); c_511 SBUF in CBF1 (written p=512)
  dec_persist<<<256, 256, 0, stream>>>(EMBs, tok, WdIH0, WdHH0, dbih0, dbhh0,
                                       WdIH1, WdHH1, dbih1, dbhh1,
                                       af, cf, ABF0, ABF1, CBF1, CBF0,
                                       oe, simt, fcW, fcb, dout);

  finalize<<<256, 256, 0, stream>>>(af, cf, dout + (size_t)BB * TT * VV);
}